// Round 6
// baseline (475.405 us; speedup 1.0000x reference)
//
#include <hip/hip_runtime.h>

#define NN 200000
#define DD 16
#define KK 16
#define FF 33   // 2*DD + 1

typedef __attribute__((ext_vector_type(8))) short bf16x8;
typedef __attribute__((ext_vector_type(4))) float f32x4;

// fp32 -> bf16 bits, round-to-nearest-even
__device__ __forceinline__ unsigned short f2bf(float f) {
    unsigned u = __float_as_uint(f);
    u += 0x7FFFu + ((u >> 16) & 1u);
    return (unsigned short)(u >> 16);
}

// ---- pre-pass: residual(d_out) = y ; tbl0 = bf16(y) ----
__global__ __launch_bounds__(256) void prep_kernel(
    const float* __restrict__ y, float* __restrict__ resid,
    unsigned short* __restrict__ tbl)
{
    const unsigned i = blockIdx.x * 256 + threadIdx.x;   // 800000 exact
    const float4 v = reinterpret_cast<const float4*>(y)[i];
    reinterpret_cast<float4*>(resid)[i] = v;
    ushort4 t;
    t.x = f2bf(v.x); t.y = f2bf(v.y); t.z = f2bf(v.z); t.w = f2bf(v.w);
    reinterpret_cast<ushort4*>(tbl)[i] = t;
}

// ---- one-shot weight packing (per-lane MFMA fragments) ----
// Layout per layer (float4 units, stride WSTRIDE):
//   [  0..191] bS0..bS2 : W1 "self" B-frags  (rows f<16 -> W1[f][g], else 0)
//   [192..383] bN0..bN2 : W1 "nb+d" B-frags  (row 0 -> W1[32][g] (dist row),
//                          rows 1..15 -> 0, rows 16..31 -> W1[f][g])
//   [384..447] W2a (g rows 0..31) ; [448..511] W2b (g row 32, rest 0)
//   [512..559] floats: b1v t=0..2  (t*64 + lane)
#define WSTRIDE 560

__global__ __launch_bounds__(64) void pack_kernel(
    const float* __restrict__ W1, const float* __restrict__ b1,
    const float* __restrict__ W2, float4* __restrict__ wpk)
{
    const int L = blockIdx.x, l = threadIdx.x, g4 = l >> 4, c16 = l & 15;
    const float* W1l = W1 + L * FF * FF;
    const float* W2l = W2 + L * FF * DD;
    float4* out = wpk + L * WSTRIDE;

#pragma unroll
    for (int t = 0; t < 3; ++t) {
        const int g = c16 + 16 * t;
        const bool gv = (g < FF);
        bf16x8 fs, fn;
#pragma unroll
        for (int j = 0; j < 8; ++j) {
            const int f = 8 * g4 + j;
            float ws_ = (gv && f < 16) ? W1l[f * FF + g] : 0.f;
            float wn;
            if (!gv)          wn = 0.f;
            else if (f == 0)  wn = W1l[32 * FF + g];      // dist row
            else if (f < 16)  wn = 0.f;                   // pad rows
            else              wn = W1l[f * FF + g];       // nb rows 16..31
            fs[j] = (short)f2bf(ws_);
            fn[j] = (short)f2bf(wn);
        }
        out[t * 64 + l]       = __builtin_bit_cast(float4, fs);
        out[192 + t * 64 + l] = __builtin_bit_cast(float4, fn);
    }
    {
        bf16x8 fa, fb;
#pragma unroll
        for (int j = 0; j < 8; ++j) {
            fa[j] = (short)f2bf(W2l[(8 * g4 + j) * DD + c16]);
            const int g = 32 + 8 * g4 + j;
            fb[j] = (short)((g < FF) ? f2bf(W2l[g * DD + c16]) : 0);
        }
        out[384 + l] = __builtin_bit_cast(float4, fa);
        out[448 + l] = __builtin_bit_cast(float4, fb);
    }
    float* wf = reinterpret_cast<float*>(out + 512);
#pragma unroll
    for (int t = 0; t < 3; ++t) {
        const int g = c16 + 16 * t;
        wf[t * 64 + l] = (g < FF) ? b1[L * FF + g] : 0.f;
    }
}

// ---- one message-passing layer, node-major stage 1, VGPR-budgeted ----
__global__ __launch_bounds__(256, 6) void layer_kernel(
    float*       __restrict__ resid,          // N x D fp32 (in-place residual)
    const unsigned short* __restrict__ tin,   // N x D bf16 (prev layer)
    unsigned short*       __restrict__ tout,  // N x D bf16 (this layer)
    const float* __restrict__ dists,          // N x K
    const int*   __restrict__ idx,            // N x K
    const float4* __restrict__ wpkL,          // packed weights, this layer
    const float* __restrict__ b2,             // D
    const float* __restrict__ gnw,            // D
    const float* __restrict__ gnb)            // D
{
    __shared__ unsigned short hsH[4][16][64];

    const int tid = threadIdx.x;
    const int w   = tid >> 6, l = tid & 63, g4 = l >> 4, c16 = l & 15;
    const int n0  = (blockIdx.x * 4 + w) * 16;
    const unsigned myrow = (unsigned)(n0 + c16);   // the node this lane "owns"
    const unsigned ibase = myrow * (unsigned)KK;

    // zero this wave's LDS slice (pad cols 33..63 must be 0 for stage-2 MFMA)
    {
        uint4 z; z.x = z.y = z.z = z.w = 0u;
        reinterpret_cast<uint4*>(&hsH[w][0][0])[l]      = z;
        reinterpret_cast<uint4*>(&hsH[w][0][0])[l + 64] = z;
    }

    const bf16x8* tinv = reinterpret_cast<const bf16x8*>(tin);
    const unsigned goff = (unsigned)(g4 & 1);

    // ---- gather pipeline prologue: idx 0..5, gathers for k=0..3 ----
    int ni0, ni1;
    bf16x8 gp[4];
    {
        const int i0 = idx[ibase + 0], i1 = idx[ibase + 1];
        const int i2 = idx[ibase + 2], i3 = idx[ibase + 3];
        gp[0] = tinv[(unsigned)i0 * 2 + goff];
        gp[1] = tinv[(unsigned)i1 * 2 + goff];
        gp[2] = tinv[(unsigned)i2 * 2 + goff];
        gp[3] = tinv[(unsigned)i3 * 2 + goff];
        ni0 = idx[ibase + 4];
        ni1 = idx[ibase + 5];
    }

    // ---- dists row -> 8 packed bf16 pairs ----
    unsigned dpk[8];
    {
        const float4* dp_ = reinterpret_cast<const float4*>(dists + (size_t)myrow * KK);
        const float4 a = dp_[0], b = dp_[1], c = dp_[2], d = dp_[3];
        dpk[0] = (unsigned)f2bf(a.x) | ((unsigned)f2bf(a.y) << 16);
        dpk[1] = (unsigned)f2bf(a.z) | ((unsigned)f2bf(a.w) << 16);
        dpk[2] = (unsigned)f2bf(b.x) | ((unsigned)f2bf(b.y) << 16);
        dpk[3] = (unsigned)f2bf(b.z) | ((unsigned)f2bf(b.w) << 16);
        dpk[4] = (unsigned)f2bf(c.x) | ((unsigned)f2bf(c.y) << 16);
        dpk[5] = (unsigned)f2bf(c.z) | ((unsigned)f2bf(c.w) << 16);
        dpk[6] = (unsigned)f2bf(d.x) | ((unsigned)f2bf(d.y) << 16);
        dpk[7] = (unsigned)f2bf(d.z) | ((unsigned)f2bf(d.w) << 16);
    }

    // ---- fragments needed DURING the loop only ----
    const bf16x8* wv8 = reinterpret_cast<const bf16x8*>(wpkL);
    const bf16x8 bN0 = wv8[192 + l], bN1 = wv8[256 + l], bN2 = wv8[320 + l];
    const float* wf = reinterpret_cast<const float*>(wpkL + 512);

    // ---- base[n][g] = b1[g] + self @ W1self   (3 one-time MFMAs; bS dies after) ----
    f32x4 base0, base1, base2;
    {
        const float b1v0 = wf[l], b1v1 = wf[64 + l], b1v2 = wf[128 + l];
        base0[0]=b1v0; base0[1]=b1v0; base0[2]=b1v0; base0[3]=b1v0;
        base1[0]=b1v1; base1[1]=b1v1; base1[2]=b1v1; base1[3]=b1v1;
        base2[0]=b1v2; base2[1]=b1v2; base2[2]=b1v2; base2[3]=b1v2;
        const bf16x8 bS0 = wv8[l], bS1 = wv8[64 + l], bS2 = wv8[128 + l];
        const bf16x8 aself = tinv[myrow * 2 + goff];
        base0 = __builtin_amdgcn_mfma_f32_16x16x32_bf16(aself, bS0, base0, 0, 0, 0);
        base1 = __builtin_amdgcn_mfma_f32_16x16x32_bf16(aself, bS1, base1, 0, 0, 0);
        base2 = __builtin_amdgcn_mfma_f32_16x16x32_bf16(aself, bS2, base2, 0, 0, 0);
    }

    f32x4 s0, s1, s2;
#pragma unroll
    for (int j = 0; j < 4; ++j) { s0[j]=0.f; s1[j]=0.f; s2[j]=0.f; }

    const bool isg0 = (g4 == 0);

#pragma unroll
    for (int k = 0; k < KK; ++k) {
        // A = [d | junk | nb_k]; only col 0 (group 0) patched (B rows 1..15 = 0)
        uint4 au = __builtin_bit_cast(uint4, gp[k & 3]);
        const unsigned db = (k & 1) ? (dpk[k >> 1] >> 16) : (dpk[k >> 1] & 0xFFFFu);
        au.x = isg0 ? db : au.x;
        const bf16x8 av = __builtin_bit_cast(bf16x8, au);

        // refill pipeline: gather k+4 (idx prefetched 2 iters earlier)
        if (k + 4 < KK) {
            const int gi = (k & 1) ? ni1 : ni0;
            gp[k & 3] = tinv[(unsigned)gi * 2 + goff];
        }
        if (k + 6 < KK) {
            if (k & 1) ni1 = idx[ibase + k + 6];
            else       ni0 = idx[ibase + k + 6];
        }

        const f32x4 a0 = __builtin_amdgcn_mfma_f32_16x16x32_bf16(av, bN0, base0, 0, 0, 0);
        const f32x4 a1 = __builtin_amdgcn_mfma_f32_16x16x32_bf16(av, bN1, base1, 0, 0, 0);
        const f32x4 a2 = __builtin_amdgcn_mfma_f32_16x16x32_bf16(av, bN2, base2, 0, 0, 0);

        // s += leaky(a) = 0.6a + 0.4|a|   (|a| free as VOP3 input modifier)
#pragma unroll
        for (int j = 0; j < 4; ++j) {
            s0[j] = fmaf(0.6f, a0[j], fmaf(0.4f, fabsf(a0[j]), s0[j]));
            s1[j] = fmaf(0.6f, a1[j], fmaf(0.4f, fabsf(a1[j]), s1[j]));
            s2[j] = fmaf(0.6f, a2[j], fmaf(0.4f, fabsf(a2[j]), s2[j]));
        }
    }

    // keep stage-2 operand loads AFTER the loop (live-range discipline)
    __builtin_amdgcn_sched_barrier(0);

    // ---- hsum -> LDS transposed (once per wave), XOR-swizzled ----
#pragma unroll
    for (int j = 0; j < 4; ++j) {
        const int node = 4 * g4 + j;
        const int sw = (node & 7) << 3;
        hsH[w][node][(c16     ) ^ sw] = f2bf(s0[j]);
        hsH[w][node][(c16 + 16) ^ sw] = f2bf(s1[j]);
        hsH[w][node][(c16 + 32) ^ sw] = f2bf(s2[j]);
    }

    // ---- stage 2: msg = hsum @ W2 + 16*b2 ----
    const bf16x8 b2ah = wv8[384 + l], b2bh = wv8[448 + l];
    const float kb2 = 16.f * b2[c16];
    const float gw = gnw[c16], gb = gnb[c16];

    const int swr = (c16 & 7) << 3;
    const unsigned short* rowH = &hsH[w][c16][0];
    const bf16x8 a2h0 = *reinterpret_cast<const bf16x8*>(rowH + ((8 * g4     ) ^ swr));
    const bf16x8 a2h1 = *reinterpret_cast<const bf16x8*>(rowH + ((8 * g4 + 32) ^ swr));

    f32x4 macc;
    macc[0] = kb2; macc[1] = kb2; macc[2] = kb2; macc[3] = kb2;
    macc = __builtin_amdgcn_mfma_f32_16x16x32_bf16(a2h0, b2ah, macc, 0, 0, 0);
    macc = __builtin_amdgcn_mfma_f32_16x16x32_bf16(a2h1, b2bh, macc, 0, 0, 0);

    // ---- group-norm + leaky + residual (in-place) + bf16 table out ----
#pragma unroll
    for (int j = 0; j < 4; ++j) {
        const float v = macc[j];
        const unsigned n = (unsigned)(n0 + 4 * g4 + j);
        float mu = v;
        mu += __shfl_xor(mu, 1); mu += __shfl_xor(mu, 2); mu += __shfl_xor(mu, 4);
        mu *= 0.125f;
        const float e = v - mu;
        float vr = e * e;
        vr += __shfl_xor(vr, 1); vr += __shfl_xor(vr, 2); vr += __shfl_xor(vr, 4);
        vr *= 0.125f;
        const float xn = e * rsqrtf(vr + 1e-5f);
        const float yv = fmaf(xn, gw, gb);
        const float val = fmaxf(yv, 0.2f * yv);
        const float o = resid[n * DD + c16] + val;
        resid[n * DD + c16] = o;
        tout [n * DD + c16] = f2bf(o);
    }
}

extern "C" void kernel_launch(void* const* d_in, const int* in_sizes, int n_in,
                              void* d_out, int out_size, void* d_ws, size_t ws_size,
                              hipStream_t stream) {
    const float* y     = (const float*)d_in[0];
    const float* dists = (const float*)d_in[1];
    const float* W1    = (const float*)d_in[2];
    const float* b1    = (const float*)d_in[3];
    const float* W2    = (const float*)d_in[4];
    const float* b2    = (const float*)d_in[5];
    const float* gnw   = (const float*)d_in[6];
    const float* gnb   = (const float*)d_in[7];
    const int*   idx   = (const int*)d_in[8];

    float* resid = (float*)d_out;                       // fp32 residual, in-place
    unsigned short* tbl0 = (unsigned short*)d_ws;       // N x D bf16
    unsigned short* tbl1 = tbl0 + (size_t)NN * DD;      // N x D bf16
    float4* wpk = (float4*)((char*)d_ws + (size_t)2 * NN * DD * 2);  // ~27 KB packed

    pack_kernel<<<3, 64, 0, stream>>>(W1, b1, W2, wpk);
    prep_kernel<<<(NN * 4) / 256, 256, 0, stream>>>(y, resid, tbl0);

    const int grid = NN / 64;   // 3125 blocks; 4 waves x 16 nodes

    layer_kernel<<<grid, 256, 0, stream>>>(
        resid, tbl0, tbl1, dists, idx, wpk + 0 * WSTRIDE,
        b2 + 0 * DD, gnw + 0 * DD, gnb + 0 * DD);

    layer_kernel<<<grid, 256, 0, stream>>>(
        resid, tbl1, tbl0, dists, idx, wpk + 1 * WSTRIDE,
        b2 + 1 * DD, gnw + 1 * DD, gnb + 1 * DD);

    layer_kernel<<<grid, 256, 0, stream>>>(
        resid, tbl0, tbl1, dists, idx, wpk + 2 * WSTRIDE,
        b2 + 2 * DD, gnw + 2 * DD, gnb + 2 * DD);
}

// Round 7
// 289.917 us; speedup vs baseline: 1.6398x; 1.6398x over previous
//
#include <hip/hip_runtime.h>

#define NN 200000
#define DD 16
#define KK 16
#define FF 33   // 2*DD + 1

typedef __attribute__((ext_vector_type(8))) short bf16x8;
typedef __attribute__((ext_vector_type(4))) float f32x4;

// fp32 -> bf16 bits, round-to-nearest-even
__device__ __forceinline__ unsigned short f2bf(float f) {
    unsigned u = __float_as_uint(f);
    u += 0x7FFFu + ((u >> 16) & 1u);
    return (unsigned short)(u >> 16);
}

// ---- pre-pass: residual(d_out) = y ; tbl0 = bf16(y) ----
__global__ __launch_bounds__(256) void prep_kernel(
    const float* __restrict__ y, float* __restrict__ resid,
    unsigned short* __restrict__ tbl)
{
    const unsigned i = blockIdx.x * 256 + threadIdx.x;   // 800000 exact
    const float4 v = reinterpret_cast<const float4*>(y)[i];
    reinterpret_cast<float4*>(resid)[i] = v;
    ushort4 t;
    t.x = f2bf(v.x); t.y = f2bf(v.y); t.z = f2bf(v.z); t.w = f2bf(v.w);
    reinterpret_cast<ushort4*>(tbl)[i] = t;
}

// ---- one-shot weight packing (per-lane MFMA fragments) ----
// Layout per layer (float4 units, stride WSTRIDE):
//   [  0..191] bS0..bS2 : W1 "self" B-frags  (rows f<16 -> W1[f][g], else 0)
//   [192..383] bN0..bN2 : W1 "nb+d" B-frags  (row 0 -> W1[32][g] (dist row),
//                          rows 1..15 -> 0, rows 16..31 -> W1[f][g])
//   [384..447] W2a (g rows 0..31) ; [448..511] W2b (g row 32, rest 0)
//   [512..559] floats: b1v t=0..2  (t*64 + lane)
#define WSTRIDE 560

__global__ __launch_bounds__(64) void pack_kernel(
    const float* __restrict__ W1, const float* __restrict__ b1,
    const float* __restrict__ W2, float4* __restrict__ wpk)
{
    const int L = blockIdx.x, l = threadIdx.x, g4 = l >> 4, c16 = l & 15;
    const float* W1l = W1 + L * FF * FF;
    const float* W2l = W2 + L * FF * DD;
    float4* out = wpk + L * WSTRIDE;

#pragma unroll
    for (int t = 0; t < 3; ++t) {
        const int g = c16 + 16 * t;
        const bool gv = (g < FF);
        bf16x8 fs, fn;
#pragma unroll
        for (int j = 0; j < 8; ++j) {
            const int f = 8 * g4 + j;
            float ws_ = (gv && f < 16) ? W1l[f * FF + g] : 0.f;
            float wn;
            if (!gv)          wn = 0.f;
            else if (f == 0)  wn = W1l[32 * FF + g];      // dist row
            else if (f < 16)  wn = 0.f;                   // pad rows
            else              wn = W1l[f * FF + g];       // nb rows 16..31
            fs[j] = (short)f2bf(ws_);
            fn[j] = (short)f2bf(wn);
        }
        out[t * 64 + l]       = __builtin_bit_cast(float4, fs);
        out[192 + t * 64 + l] = __builtin_bit_cast(float4, fn);
    }
    {
        bf16x8 fa, fb;
#pragma unroll
        for (int j = 0; j < 8; ++j) {
            fa[j] = (short)f2bf(W2l[(8 * g4 + j) * DD + c16]);
            const int g = 32 + 8 * g4 + j;
            fb[j] = (short)((g < FF) ? f2bf(W2l[g * DD + c16]) : 0);
        }
        out[384 + l] = __builtin_bit_cast(float4, fa);
        out[448 + l] = __builtin_bit_cast(float4, fb);
    }
    float* wf = reinterpret_cast<float*>(out + 512);
#pragma unroll
    for (int t = 0; t < 3; ++t) {
        const int g = c16 + 16 * t;
        wf[t * 64 + l] = (g < FF) ? b1[L * FF + g] : 0.f;
    }
}

// ---- one message-passing layer, node-major stage 1, lean live set ----
__global__ __launch_bounds__(256, 5) void layer_kernel(
    float*       __restrict__ resid,          // N x D fp32 (in-place residual)
    const unsigned short* __restrict__ tin,   // N x D bf16 (prev layer)
    unsigned short*       __restrict__ tout,  // N x D bf16 (this layer)
    const float* __restrict__ dists,          // N x K
    const int*   __restrict__ idx,            // N x K
    const float4* __restrict__ wpkL,          // packed weights, this layer
    const float* __restrict__ b2,             // D
    const float* __restrict__ gnw,            // D
    const float* __restrict__ gnb)            // D
{
    __shared__ unsigned short hsH[4][16][64];

    const int tid = threadIdx.x;
    const int w   = tid >> 6, l = tid & 63, g4 = l >> 4, c16 = l & 15;
    const int n0  = (blockIdx.x * 4 + w) * 16;
    const unsigned myrow = (unsigned)(n0 + c16);   // the node this lane "owns"
    const unsigned ibase = myrow * (unsigned)KK;

    // zero this wave's LDS slice (pad cols 33..63 must be 0 for stage-2 MFMA)
    {
        uint4 z; z.x = z.y = z.z = z.w = 0u;
        reinterpret_cast<uint4*>(&hsH[w][0][0])[l]      = z;
        reinterpret_cast<uint4*>(&hsH[w][0][0])[l + 64] = z;
    }

    const bf16x8* tinv = reinterpret_cast<const bf16x8*>(tin);
    const unsigned goff = (unsigned)(g4 & 1);

    // ---- gather pipeline prologue: 3-deep gathers, 2-reg rolling idx ----
    int ni0, ni1;
    bf16x8 gp[3];
    {
        const int i0 = idx[ibase + 0], i1 = idx[ibase + 1], i2 = idx[ibase + 2];
        gp[0] = tinv[(unsigned)i0 * 2 + goff];
        gp[1] = tinv[(unsigned)i1 * 2 + goff];
        gp[2] = tinv[(unsigned)i2 * 2 + goff];
        ni0 = idx[ibase + 3];
        ni1 = idx[ibase + 4];
    }

    // ---- dists row -> 8 packed bf16 pairs ----
    unsigned dpk[8];
    {
        const float4* dp_ = reinterpret_cast<const float4*>(dists + (size_t)myrow * KK);
        const float4 a = dp_[0], b = dp_[1], c = dp_[2], d = dp_[3];
        dpk[0] = (unsigned)f2bf(a.x) | ((unsigned)f2bf(a.y) << 16);
        dpk[1] = (unsigned)f2bf(a.z) | ((unsigned)f2bf(a.w) << 16);
        dpk[2] = (unsigned)f2bf(b.x) | ((unsigned)f2bf(b.y) << 16);
        dpk[3] = (unsigned)f2bf(b.z) | ((unsigned)f2bf(b.w) << 16);
        dpk[4] = (unsigned)f2bf(c.x) | ((unsigned)f2bf(c.y) << 16);
        dpk[5] = (unsigned)f2bf(c.z) | ((unsigned)f2bf(c.w) << 16);
        dpk[6] = (unsigned)f2bf(d.x) | ((unsigned)f2bf(d.y) << 16);
        dpk[7] = (unsigned)f2bf(d.z) | ((unsigned)f2bf(d.w) << 16);
    }

    // ---- fragments needed DURING the loop only ----
    const bf16x8* wv8 = reinterpret_cast<const bf16x8*>(wpkL);
    const bf16x8 bN0 = wv8[192 + l], bN1 = wv8[256 + l], bN2 = wv8[320 + l];
    const float* wf = reinterpret_cast<const float*>(wpkL + 512);

    // ---- base[n][g] = b1[g] + self @ W1self   (3 one-time MFMAs; bS dies after) ----
    f32x4 base0, base1, base2;
    {
        const float b1v0 = wf[l], b1v1 = wf[64 + l], b1v2 = wf[128 + l];
        base0[0]=b1v0; base0[1]=b1v0; base0[2]=b1v0; base0[3]=b1v0;
        base1[0]=b1v1; base1[1]=b1v1; base1[2]=b1v1; base1[3]=b1v1;
        base2[0]=b1v2; base2[1]=b1v2; base2[2]=b1v2; base2[3]=b1v2;
        const bf16x8 bS0 = wv8[l], bS1 = wv8[64 + l], bS2 = wv8[128 + l];
        const bf16x8 aself = tinv[myrow * 2 + goff];
        base0 = __builtin_amdgcn_mfma_f32_16x16x32_bf16(aself, bS0, base0, 0, 0, 0);
        base1 = __builtin_amdgcn_mfma_f32_16x16x32_bf16(aself, bS1, base1, 0, 0, 0);
        base2 = __builtin_amdgcn_mfma_f32_16x16x32_bf16(aself, bS2, base2, 0, 0, 0);
    }

    f32x4 s0, s1, s2;
#pragma unroll
    for (int j = 0; j < 4; ++j) { s0[j]=0.f; s1[j]=0.f; s2[j]=0.f; }

    const bool isg0 = (g4 == 0);

#pragma unroll
    for (int k = 0; k < KK; ++k) {
        // A = [d | junk | nb_k]; only col 0 (group 0) patched (B rows 1..15 = 0)
        uint4 au = __builtin_bit_cast(uint4, gp[k % 3]);
        const unsigned db = (k & 1) ? (dpk[k >> 1] >> 16) : (dpk[k >> 1] & 0xFFFFu);
        au.x = isg0 ? db : au.x;
        const bf16x8 av = __builtin_bit_cast(bf16x8, au);

        // refill: gather k+3 (idx value loaded 2 iters earlier), idx k+5
        if (k < KK - 3) {
            const int gi = (k & 1) ? ni1 : ni0;
            gp[k % 3] = tinv[(unsigned)gi * 2 + goff];
        }
        if (k < KK - 5) {
            if (k & 1) ni1 = idx[ibase + k + 5];
            else       ni0 = idx[ibase + k + 5];
        }

        const f32x4 a0 = __builtin_amdgcn_mfma_f32_16x16x32_bf16(av, bN0, base0, 0, 0, 0);
        const f32x4 a1 = __builtin_amdgcn_mfma_f32_16x16x32_bf16(av, bN1, base1, 0, 0, 0);
        const f32x4 a2 = __builtin_amdgcn_mfma_f32_16x16x32_bf16(av, bN2, base2, 0, 0, 0);

        // s += leaky(a) = 0.6a + 0.4|a|   (|a| free as VOP3 input modifier)
#pragma unroll
        for (int j = 0; j < 4; ++j) {
            s0[j] = fmaf(0.6f, a0[j], fmaf(0.4f, fabsf(a0[j]), s0[j]));
            s1[j] = fmaf(0.6f, a1[j], fmaf(0.4f, fabsf(a1[j]), s1[j]));
            s2[j] = fmaf(0.6f, a2[j], fmaf(0.4f, fabsf(a2[j]), s2[j]));
        }
    }

    // keep stage-2 operand loads AFTER the loop (live-range discipline)
    __builtin_amdgcn_sched_barrier(0);

    // ---- hsum -> LDS transposed (once per wave), XOR-swizzled ----
#pragma unroll
    for (int j = 0; j < 4; ++j) {
        const int node = 4 * g4 + j;
        const int sw = (node & 7) << 3;
        hsH[w][node][(c16     ) ^ sw] = f2bf(s0[j]);
        hsH[w][node][(c16 + 16) ^ sw] = f2bf(s1[j]);
        hsH[w][node][(c16 + 32) ^ sw] = f2bf(s2[j]);
    }

    // ---- stage 2: msg = hsum @ W2 + 16*b2 ----
    const bf16x8 b2ah = wv8[384 + l], b2bh = wv8[448 + l];
    const float kb2 = 16.f * b2[c16];
    const float gw = gnw[c16], gb = gnb[c16];

    const int swr = (c16 & 7) << 3;
    const unsigned short* rowH = &hsH[w][c16][0];
    const bf16x8 a2h0 = *reinterpret_cast<const bf16x8*>(rowH + ((8 * g4     ) ^ swr));
    const bf16x8 a2h1 = *reinterpret_cast<const bf16x8*>(rowH + ((8 * g4 + 32) ^ swr));

    f32x4 macc;
    macc[0] = kb2; macc[1] = kb2; macc[2] = kb2; macc[3] = kb2;
    macc = __builtin_amdgcn_mfma_f32_16x16x32_bf16(a2h0, b2ah, macc, 0, 0, 0);
    macc = __builtin_amdgcn_mfma_f32_16x16x32_bf16(a2h1, b2bh, macc, 0, 0, 0);

    // ---- group-norm + leaky + residual (in-place) + bf16 table out ----
#pragma unroll
    for (int j = 0; j < 4; ++j) {
        const float v = macc[j];
        const unsigned n = (unsigned)(n0 + 4 * g4 + j);
        float mu = v;
        mu += __shfl_xor(mu, 1); mu += __shfl_xor(mu, 2); mu += __shfl_xor(mu, 4);
        mu *= 0.125f;
        const float e = v - mu;
        float vr = e * e;
        vr += __shfl_xor(vr, 1); vr += __shfl_xor(vr, 2); vr += __shfl_xor(vr, 4);
        vr *= 0.125f;
        const float xn = e * rsqrtf(vr + 1e-5f);
        const float yv = fmaf(xn, gw, gb);
        const float val = fmaxf(yv, 0.2f * yv);
        const float o = resid[n * DD + c16] + val;
        resid[n * DD + c16] = o;
        tout [n * DD + c16] = f2bf(o);
    }
}

extern "C" void kernel_launch(void* const* d_in, const int* in_sizes, int n_in,
                              void* d_out, int out_size, void* d_ws, size_t ws_size,
                              hipStream_t stream) {
    const float* y     = (const float*)d_in[0];
    const float* dists = (const float*)d_in[1];
    const float* W1    = (const float*)d_in[2];
    const float* b1    = (const float*)d_in[3];
    const float* W2    = (const float*)d_in[4];
    const float* b2    = (const float*)d_in[5];
    const float* gnw   = (const float*)d_in[6];
    const float* gnb   = (const float*)d_in[7];
    const int*   idx   = (const int*)d_in[8];

    float* resid = (float*)d_out;                       // fp32 residual, in-place
    unsigned short* tbl0 = (unsigned short*)d_ws;       // N x D bf16
    unsigned short* tbl1 = tbl0 + (size_t)NN * DD;      // N x D bf16
    float4* wpk = (float4*)((char*)d_ws + (size_t)2 * NN * DD * 2);  // ~27 KB packed

    pack_kernel<<<3, 64, 0, stream>>>(W1, b1, W2, wpk);
    prep_kernel<<<(NN * 4) / 256, 256, 0, stream>>>(y, resid, tbl0);

    const int grid = NN / 64;   // 3125 blocks; 4 waves x 16 nodes

    layer_kernel<<<grid, 256, 0, stream>>>(
        resid, tbl0, tbl1, dists, idx, wpk + 0 * WSTRIDE,
        b2 + 0 * DD, gnw + 0 * DD, gnb + 0 * DD);

    layer_kernel<<<grid, 256, 0, stream>>>(
        resid, tbl1, tbl0, dists, idx, wpk + 1 * WSTRIDE,
        b2 + 1 * DD, gnw + 1 * DD, gnb + 1 * DD);

    layer_kernel<<<grid, 256, 0, stream>>>(
        resid, tbl0, tbl1, dists, idx, wpk + 2 * WSTRIDE,
        b2 + 2 * DD, gnw + 2 * DD, gnb + 2 * DD);
}

// Round 8
// 213.371 us; speedup vs baseline: 2.2281x; 1.3587x over previous
//
#include <hip/hip_runtime.h>

#define NN 200000
#define DD 16
#define KK 16
#define FF 33   // 2*DD + 1

typedef __attribute__((ext_vector_type(8))) short bf16x8;
typedef __attribute__((ext_vector_type(4))) float f32x4;

// fp32 -> bf16 bits, round-to-nearest-even
__device__ __forceinline__ unsigned short f2bf(float f) {
    unsigned u = __float_as_uint(f);
    u += 0x7FFFu + ((u >> 16) & 1u);
    return (unsigned short)(u >> 16);
}

// ---- pre-pass: residual(d_out) = y ; tbl0 = bf16(y) ----
__global__ __launch_bounds__(256) void prep_kernel(
    const float* __restrict__ y, float* __restrict__ resid,
    unsigned short* __restrict__ tbl)
{
    const unsigned i = blockIdx.x * 256 + threadIdx.x;   // 800000 exact
    const float4 v = reinterpret_cast<const float4*>(y)[i];
    reinterpret_cast<float4*>(resid)[i] = v;
    ushort4 t;
    t.x = f2bf(v.x); t.y = f2bf(v.y); t.z = f2bf(v.z); t.w = f2bf(v.w);
    reinterpret_cast<ushort4*>(tbl)[i] = t;
}

// ---- one-shot weight packing (per-lane MFMA fragments) ----
// Layout per layer (float4 units, stride WSTRIDE):
//   [  0..191] bS0..bS2 : W1 "self" B-frags  (rows f<16 -> W1[f][g], else 0)
//   [192..383] bN0..bN2 : W1 "nb+d" B-frags  (row 0 -> W1[32][g] (dist row),
//                          rows 1..15 -> 0, rows 16..31 -> W1[f][g])
//   [384..447] W2a (g rows 0..31) ; [448..511] W2b (g row 32, rest 0)
//   [512..559] floats: b1v t=0..2  (t*64 + lane)
#define WSTRIDE 560

__global__ __launch_bounds__(64) void pack_kernel(
    const float* __restrict__ W1, const float* __restrict__ b1,
    const float* __restrict__ W2, float4* __restrict__ wpk)
{
    const int L = blockIdx.x, l = threadIdx.x, g4 = l >> 4, c16 = l & 15;
    const float* W1l = W1 + L * FF * FF;
    const float* W2l = W2 + L * FF * DD;
    float4* out = wpk + L * WSTRIDE;

#pragma unroll
    for (int t = 0; t < 3; ++t) {
        const int g = c16 + 16 * t;
        const bool gv = (g < FF);
        bf16x8 fs, fn;
#pragma unroll
        for (int j = 0; j < 8; ++j) {
            const int f = 8 * g4 + j;
            float ws_ = (gv && f < 16) ? W1l[f * FF + g] : 0.f;
            float wn;
            if (!gv)          wn = 0.f;
            else if (f == 0)  wn = W1l[32 * FF + g];      // dist row
            else if (f < 16)  wn = 0.f;                   // pad rows
            else              wn = W1l[f * FF + g];       // nb rows 16..31
            fs[j] = (short)f2bf(ws_);
            fn[j] = (short)f2bf(wn);
        }
        out[t * 64 + l]       = __builtin_bit_cast(float4, fs);
        out[192 + t * 64 + l] = __builtin_bit_cast(float4, fn);
    }
    {
        bf16x8 fa, fb;
#pragma unroll
        for (int j = 0; j < 8; ++j) {
            fa[j] = (short)f2bf(W2l[(8 * g4 + j) * DD + c16]);
            const int g = 32 + 8 * g4 + j;
            fb[j] = (short)((g < FF) ? f2bf(W2l[g * DD + c16]) : 0);
        }
        out[384 + l] = __builtin_bit_cast(float4, fa);
        out[448 + l] = __builtin_bit_cast(float4, fb);
    }
    float* wf = reinterpret_cast<float*>(out + 512);
#pragma unroll
    for (int t = 0; t < 3; ++t) {
        const int g = c16 + 16 * t;
        wf[t * 64 + l] = (g < FF) ? b1[L * FF + g] : 0.f;
    }
}

// ---- one message-passing layer, node-major, 2x8 gather pipeline ----
__global__ __launch_bounds__(256, 4) void layer_kernel(
    float*       __restrict__ resid,          // N x D fp32 (in-place residual)
    const unsigned short* __restrict__ tin,   // N x D bf16 (prev layer)
    unsigned short*       __restrict__ tout,  // N x D bf16 (this layer)
    const float* __restrict__ dists,          // N x K
    const int*   __restrict__ idx,            // N x K
    const float4* __restrict__ wpkL,          // packed weights, this layer
    const float* __restrict__ b2,             // D
    const float* __restrict__ gnw,            // D
    const float* __restrict__ gnb)            // D
{
    __shared__ unsigned short hsH[4][16][64];

    const int tid = threadIdx.x;
    const int w   = tid >> 6, l = tid & 63, g4 = l >> 4, c16 = l & 15;
    const int n0  = (blockIdx.x * 4 + w) * 16;
    const unsigned myrow = (unsigned)(n0 + c16);   // the node this lane "owns"

    // zero this wave's LDS slice (pad cols 33..63 must be 0 for stage-2 MFMA)
    {
        uint4 z; z.x = z.y = z.z = z.w = 0u;
        reinterpret_cast<uint4*>(&hsH[w][0][0])[l]      = z;
        reinterpret_cast<uint4*>(&hsH[w][0][0])[l + 64] = z;
    }

    const bf16x8* tinv = reinterpret_cast<const bf16x8*>(tin);
    const unsigned goff = (unsigned)(g4 & 1);

    // ---- issue first 8 gathers up front (idx batch 1 is transient) ----
    bf16x8 gp[8];
    {
        const int4* ip = reinterpret_cast<const int4*>(idx + (size_t)myrow * KK);
        const int4 ia = ip[0], ib = ip[1];
        gp[0] = tinv[(unsigned)ia.x * 2 + goff];
        gp[1] = tinv[(unsigned)ia.y * 2 + goff];
        gp[2] = tinv[(unsigned)ia.z * 2 + goff];
        gp[3] = tinv[(unsigned)ia.w * 2 + goff];
        gp[4] = tinv[(unsigned)ib.x * 2 + goff];
        gp[5] = tinv[(unsigned)ib.y * 2 + goff];
        gp[6] = tinv[(unsigned)ib.z * 2 + goff];
        gp[7] = tinv[(unsigned)ib.w * 2 + goff];
    }
    // idx batch 2: lives through half A only
    int4 i2a, i2b;
    {
        const int4* ip = reinterpret_cast<const int4*>(idx + (size_t)myrow * KK);
        i2a = ip[2]; i2b = ip[3];
    }

    // ---- dists row -> 8 packed bf16 pairs ----
    unsigned dpk[8];
    {
        const float4* dp_ = reinterpret_cast<const float4*>(dists + (size_t)myrow * KK);
        const float4 a = dp_[0], b = dp_[1], c = dp_[2], d = dp_[3];
        dpk[0] = (unsigned)f2bf(a.x) | ((unsigned)f2bf(a.y) << 16);
        dpk[1] = (unsigned)f2bf(a.z) | ((unsigned)f2bf(a.w) << 16);
        dpk[2] = (unsigned)f2bf(b.x) | ((unsigned)f2bf(b.y) << 16);
        dpk[3] = (unsigned)f2bf(b.z) | ((unsigned)f2bf(b.w) << 16);
        dpk[4] = (unsigned)f2bf(c.x) | ((unsigned)f2bf(c.y) << 16);
        dpk[5] = (unsigned)f2bf(c.z) | ((unsigned)f2bf(c.w) << 16);
        dpk[6] = (unsigned)f2bf(d.x) | ((unsigned)f2bf(d.y) << 16);
        dpk[7] = (unsigned)f2bf(d.z) | ((unsigned)f2bf(d.w) << 16);
    }

    // ---- loop-resident weight fragments ----
    const bf16x8* wv8 = reinterpret_cast<const bf16x8*>(wpkL);
    const bf16x8 bN0 = wv8[192 + l], bN1 = wv8[256 + l], bN2 = wv8[320 + l];
    const float* wf = reinterpret_cast<const float*>(wpkL + 512);

    // ---- base[n][g] = b1[g] + self @ W1self   (3 one-time MFMAs; bS dies here) ----
    f32x4 base0, base1, base2;
    {
        const float b1v0 = wf[l], b1v1 = wf[64 + l], b1v2 = wf[128 + l];
        base0[0]=b1v0; base0[1]=b1v0; base0[2]=b1v0; base0[3]=b1v0;
        base1[0]=b1v1; base1[1]=b1v1; base1[2]=b1v1; base1[3]=b1v1;
        base2[0]=b1v2; base2[1]=b1v2; base2[2]=b1v2; base2[3]=b1v2;
        const bf16x8 bS0 = wv8[l], bS1 = wv8[64 + l], bS2 = wv8[128 + l];
        const bf16x8 aself = tinv[myrow * 2 + goff];
        base0 = __builtin_amdgcn_mfma_f32_16x16x32_bf16(aself, bS0, base0, 0, 0, 0);
        base1 = __builtin_amdgcn_mfma_f32_16x16x32_bf16(aself, bS1, base1, 0, 0, 0);
        base2 = __builtin_amdgcn_mfma_f32_16x16x32_bf16(aself, bS2, base2, 0, 0, 0);
    }

    f32x4 s0, s1, s2;
#pragma unroll
    for (int j = 0; j < 4; ++j) { s0[j]=0.f; s1[j]=0.f; s2[j]=0.f; }

    const bool isg0 = (g4 == 0);

    // one iteration body; all indices compile-time
#define ITER(K, REFILL_IDX)                                                   \
    {                                                                         \
        uint4 au = __builtin_bit_cast(uint4, gp[(K) & 7]);                    \
        const unsigned db = ((K) & 1) ? (dpk[(K) >> 1] >> 16)                 \
                                      : (dpk[(K) >> 1] & 0xFFFFu);            \
        au.x = isg0 ? db : au.x;                                              \
        const bf16x8 av = __builtin_bit_cast(bf16x8, au);                     \
        if ((K) < 8)                                                          \
            gp[(K) & 7] = tinv[(unsigned)(REFILL_IDX) * 2 + goff];            \
        const f32x4 a0 = __builtin_amdgcn_mfma_f32_16x16x32_bf16(av, bN0, base0, 0, 0, 0); \
        const f32x4 a1 = __builtin_amdgcn_mfma_f32_16x16x32_bf16(av, bN1, base1, 0, 0, 0); \
        const f32x4 a2 = __builtin_amdgcn_mfma_f32_16x16x32_bf16(av, bN2, base2, 0, 0, 0); \
        _Pragma("unroll")                                                     \
        for (int j = 0; j < 4; ++j) {                                         \
            s0[j] = fmaf(0.6f, a0[j], fmaf(0.4f, fabsf(a0[j]), s0[j]));       \
            s1[j] = fmaf(0.6f, a1[j], fmaf(0.4f, fabsf(a1[j]), s1[j]));       \
            s2[j] = fmaf(0.6f, a2[j], fmaf(0.4f, fabsf(a2[j]), s2[j]));       \
        }                                                                     \
    }

    // half A: consume k=0..7, refill slots with gathers for k=8..15
    ITER(0, i2a.x)  ITER(1, i2a.y)  ITER(2, i2a.z)  ITER(3, i2a.w)
    ITER(4, i2b.x)  ITER(5, i2b.y)  ITER(6, i2b.z)  ITER(7, i2b.w)
    // half B: consume k=8..15 (no refill)
    ITER(8, 0)  ITER(9, 0)  ITER(10, 0) ITER(11, 0)
    ITER(12, 0) ITER(13, 0) ITER(14, 0) ITER(15, 0)
#undef ITER

    // keep stage-2 operand loads AFTER the loop (live-range discipline)
    __builtin_amdgcn_sched_barrier(0);

    // ---- hsum -> LDS transposed (once per wave), XOR-swizzled ----
#pragma unroll
    for (int j = 0; j < 4; ++j) {
        const int node = 4 * g4 + j;
        const int sw = (node & 7) << 3;
        hsH[w][node][(c16     ) ^ sw] = f2bf(s0[j]);
        hsH[w][node][(c16 + 16) ^ sw] = f2bf(s1[j]);
        hsH[w][node][(c16 + 32) ^ sw] = f2bf(s2[j]);
    }

    // ---- stage 2: msg = hsum @ W2 + 16*b2 ----
    const bf16x8 b2ah = wv8[384 + l], b2bh = wv8[448 + l];
    const float kb2 = 16.f * b2[c16];
    const float gw = gnw[c16], gb = gnb[c16];

    const int swr = (c16 & 7) << 3;
    const unsigned short* rowH = &hsH[w][c16][0];
    const bf16x8 a2h0 = *reinterpret_cast<const bf16x8*>(rowH + ((8 * g4     ) ^ swr));
    const bf16x8 a2h1 = *reinterpret_cast<const bf16x8*>(rowH + ((8 * g4 + 32) ^ swr));

    f32x4 macc;
    macc[0] = kb2; macc[1] = kb2; macc[2] = kb2; macc[3] = kb2;
    macc = __builtin_amdgcn_mfma_f32_16x16x32_bf16(a2h0, b2ah, macc, 0, 0, 0);
    macc = __builtin_amdgcn_mfma_f32_16x16x32_bf16(a2h1, b2bh, macc, 0, 0, 0);

    // ---- group-norm + leaky + residual (in-place) + bf16 table out ----
#pragma unroll
    for (int j = 0; j < 4; ++j) {
        const float v = macc[j];
        const unsigned n = (unsigned)(n0 + 4 * g4 + j);
        float mu = v;
        mu += __shfl_xor(mu, 1); mu += __shfl_xor(mu, 2); mu += __shfl_xor(mu, 4);
        mu *= 0.125f;
        const float e = v - mu;
        float vr = e * e;
        vr += __shfl_xor(vr, 1); vr += __shfl_xor(vr, 2); vr += __shfl_xor(vr, 4);
        vr *= 0.125f;
        const float xn = e * rsqrtf(vr + 1e-5f);
        const float yv = fmaf(xn, gw, gb);
        const float val = fmaxf(yv, 0.2f * yv);
        const float o = resid[n * DD + c16] + val;
        resid[n * DD + c16] = o;
        tout [n * DD + c16] = f2bf(o);
    }
}

extern "C" void kernel_launch(void* const* d_in, const int* in_sizes, int n_in,
                              void* d_out, int out_size, void* d_ws, size_t ws_size,
                              hipStream_t stream) {
    const float* y     = (const float*)d_in[0];
    const float* dists = (const float*)d_in[1];
    const float* W1    = (const float*)d_in[2];
    const float* b1    = (const float*)d_in[3];
    const float* W2    = (const float*)d_in[4];
    const float* b2    = (const float*)d_in[5];
    const float* gnw   = (const float*)d_in[6];
    const float* gnb   = (const float*)d_in[7];
    const int*   idx   = (const int*)d_in[8];

    float* resid = (float*)d_out;                       // fp32 residual, in-place
    unsigned short* tbl0 = (unsigned short*)d_ws;       // N x D bf16
    unsigned short* tbl1 = tbl0 + (size_t)NN * DD;      // N x D bf16
    float4* wpk = (float4*)((char*)d_ws + (size_t)2 * NN * DD * 2);  // ~27 KB packed

    pack_kernel<<<3, 64, 0, stream>>>(W1, b1, W2, wpk);
    prep_kernel<<<(NN * 4) / 256, 256, 0, stream>>>(y, resid, tbl0);

    const int grid = NN / 64;   // 3125 blocks; 4 waves x 16 nodes

    layer_kernel<<<grid, 256, 0, stream>>>(
        resid, tbl0, tbl1, dists, idx, wpk + 0 * WSTRIDE,
        b2 + 0 * DD, gnw + 0 * DD, gnb + 0 * DD);

    layer_kernel<<<grid, 256, 0, stream>>>(
        resid, tbl1, tbl0, dists, idx, wpk + 1 * WSTRIDE,
        b2 + 1 * DD, gnw + 1 * DD, gnb + 1 * DD);

    layer_kernel<<<grid, 256, 0, stream>>>(
        resid, tbl0, tbl1, dists, idx, wpk + 2 * WSTRIDE,
        b2 + 2 * DD, gnw + 2 * DD, gnb + 2 * DD);
}